// Round 4
// baseline (167.320 us; speedup 1.0000x reference)
//
#include <hip/hip_runtime.h>
#include <hip/hip_bf16.h>
#include <hip/hip_fp16.h>

typedef _Float16 half8_t __attribute__((ext_vector_type(8)));
typedef _Float16 half4_t __attribute__((ext_vector_type(4)));
typedef short    short8_t __attribute__((ext_vector_type(8)));
typedef float    f32x4    __attribute__((ext_vector_type(4)));

// ---------------------------------------------------------------------------
// Kernel 1 (v3): f = x@Wf+bf (f16), g = x@Wg+bg (f16),
// vT2 = x@Wh+bh (bf16) in MFMA-B-fragment tiling:
//   vT2[b][k>>5][(k>>3)&3][ch][k&7]   (per batch: 128*4*64*8 = 262144 shorts)
// so an attn B-frag (ch = l15+16ct, keys k0+quad*8..+7) is 16 contiguous bytes.
// 512 blocks x 256 thr; block = 32 positions; thread = 10 of 80 concat chans.
// ---------------------------------------------------------------------------
__global__ __launch_bounds__(256) void prep_kernel(
    const float* __restrict__ x,
    const float* __restrict__ Wf, const float* __restrict__ bf,
    const float* __restrict__ Wg, const float* __restrict__ bg,
    const float* __restrict__ Wh, const float* __restrict__ bh,
    _Float16* __restrict__ fh, _Float16* __restrict__ gh,
    unsigned short* __restrict__ vT)
{
  __shared__ float XsT[64 * 33];   // [c][pos], pad 33 -> conflict-free
  __shared__ float Wall[64 * 80];  // [c][ch]; ch 0-7 = Wf, 8-15 = Wg, 16-79 = Wh
  __shared__ float ball[80];
  const int t  = threadIdx.x;
  const int p0 = blockIdx.x * 32;  // flat position base (B*N)

  for (int i = t; i < 512; i += 256) {
    Wall[(i >> 3) * 80 + (i & 7)]     = Wf[i];
    Wall[(i >> 3) * 80 + 8 + (i & 7)] = Wg[i];
  }
  for (int i = t; i < 4096; i += 256)
    Wall[(i >> 6) * 80 + 16 + (i & 63)] = Wh[i];
  if (t < 80) ball[t] = (t < 8) ? bf[t] : (t < 16) ? bg[t - 8] : bh[t - 16];

  const float4* xs = (const float4*)(x + (size_t)p0 * 64);
#pragma unroll
  for (int i = 0; i < 2; i++) {
    int idx = t + i * 256;          // 512 float4 = 32 rows x 16
    int row = idx >> 4, c4 = idx & 15;
    float4 v = xs[idx];
    XsT[(c4 * 4 + 0) * 33 + row] = v.x;
    XsT[(c4 * 4 + 1) * 33 + row] = v.y;
    XsT[(c4 * 4 + 2) * 33 + row] = v.z;
    XsT[(c4 * 4 + 3) * 33 + row] = v.w;
  }
  __syncthreads();

  const int pos = t & 31;
  const int g   = t >> 5;          // 0..7
  const int cb  = g * 10;          // channel base (even -> float2-aligned)

  float acc[10];
#pragma unroll
  for (int j = 0; j < 10; j++) acc[j] = ball[cb + j];

  for (int c = 0; c < 64; c++) {
    float xv = XsT[c * 33 + pos];
    const float2* wr = (const float2*)&Wall[c * 80 + cb];
#pragma unroll
    for (int k = 0; k < 5; k++) {
      float2 w2 = wr[k];
      acc[2 * k]     += xv * w2.x;
      acc[2 * k + 1] += xv * w2.y;
    }
  }

  const size_t pg = (size_t)p0 + pos;
  const int b = (int)(pg >> 12);
  const int n = (int)(pg & 4095);
  // fragment-tiled vT base for this (b, n)
  const size_t vidx = (((size_t)b * 128 + (n >> 5)) * 4 + ((n >> 3) & 3)) * 512 + (n & 7);
#pragma unroll
  for (int j = 0; j < 10; j++) {
    int ch = cb + j;
    if (ch < 8) {
      fh[pg * 8 + ch] = (_Float16)acc[j];
    } else if (ch < 16) {
      gh[pg * 8 + (ch - 8)] = (_Float16)acc[j];
    } else {
      __hip_bfloat16 hv = __float2bfloat16(acc[j]);
      vT[vidx + (size_t)(ch - 16) * 8] = *(unsigned short*)&hv;
    }
  }
}

// ---------------------------------------------------------------------------
// Kernel 2 (v4): flash attention, no-max softmax (logits bounded << 88).
// 1024 blocks x 512 thr (8 waves). Block = one (batch, 16-query tile); wave w
// handles keys [w*512, w*512+512). Partial (acc, l) combined through LDS.
// __launch_bounds__(512,8) caps VGPR at 64 -> 4 blocks/CU = 32 waves/CU.
// ---------------------------------------------------------------------------
__device__ __forceinline__ unsigned pack_bf16_2(float lo, float hi) {
  float2 f2; f2.x = lo; f2.y = hi;
  __hip_bfloat162 h2 = __float22bfloat162_rn(f2);
  return *reinterpret_cast<unsigned*>(&h2);
}

__global__ __launch_bounds__(512, 8) void attn_kernel(
    const _Float16* __restrict__ fh,        // [B][N][8] f16
    const _Float16* __restrict__ gh,        // [B][N][8] f16
    const unsigned short* __restrict__ vT,  // frag-tiled, see prep
    float* __restrict__ out)                // [B][N][64] f32
{
  const int N    = 4096;
  const int lane = threadIdx.x & 63;
  const int w    = threadIdx.x >> 6;       // 0..7
  const int quad = lane >> 4;
  const int l15  = lane & 15;

  __shared__ float red[7][64][17];  // waves 1-7: 16 acc + 1 l per lane

  // XCD swizzle: batch b on XCDs {2b,2b+1} -> f/g/vT stay in that L2 pair
  const int xcd = blockIdx.x & 7;
  const int b   = xcd >> 1;
  const int sub = ((blockIdx.x >> 3) << 1) + (xcd & 1);  // 0..255 query tile
  const int q0  = sub * 16;
  const int kbase = w * 512;

  const _Float16* fbase = fh + (size_t)b * N * 8;
  const _Float16* gbase = gh + (size_t)b * N * 8;
  // lane-fixed part of the frag-tiled vT address
  const short* vbat = (const short*)vT + (size_t)b * 262144 + (quad << 9) + (l15 << 3);

  // G B-frag: B[k=quad*8+j][n=q=l15]; only quad 0 carries real k (DK=8)
  half8_t gfrag = {};
  if (quad == 0) gfrag = *(const half8_t*)(gbase + (size_t)(q0 + l15) * 8);

  const f32x4 zc = {0.f, 0.f, 0.f, 0.f};
  f32x4 acc[4] = {zc, zc, zc, zc};   // D[q=quad*4+reg][chan=ct*16+l15]
  float lpart = 0.f;

  const int  srcA = ((quad & 1) << 5) + l15;  // source lanes for C->A transform
  const int  srcB = srcA + 16;
  const bool hi   = (quad >= 2);

#pragma unroll 8
  for (int cc = 0; cc < 16; cc++) {
    const int k0 = kbase + cc * 32;

    // ---- scores: S^T[key][q], two 16-key tiles; loads masked to quad 0
    half8_t f0 = {}, f1 = {};
    if (quad == 0) {
      f0 = *(const half8_t*)(fbase + (size_t)(k0 + l15) * 8);
      f1 = *(const half8_t*)(fbase + (size_t)(k0 + 16 + l15) * 8);
    }
    f32x4 s0 = __builtin_amdgcn_mfma_f32_16x16x32_f16(f0, gfrag, zc, 0, 0, 0);
    f32x4 s1 = __builtin_amdgcn_mfma_f32_16x16x32_f16(f1, gfrag, zc, 0, 0, 0);
    // lane holds S^T[key = k0 + 16t + quad*4 + reg][q = l15]

    float p00 = __expf(s0[0]), p01 = __expf(s0[1]), p02 = __expf(s0[2]), p03 = __expf(s0[3]);
    float p10 = __expf(s1[0]), p11 = __expf(s1[1]), p12 = __expf(s1[2]), p13 = __expf(s1[3]);
    lpart += (p00 + p01 + p02 + p03) + (p10 + p11 + p12 + p13);

    unsigned pk00 = pack_bf16_2(p00, p01), pk01 = pack_bf16_2(p02, p03);
    unsigned pk10 = pack_bf16_2(p10, p11), pk11 = pack_bf16_2(p12, p13);

    // C-layout -> A-layout: lane (quad,l15) needs P[q=l15][kk=quad*8+j]
    unsigned t0aA = __shfl((int)pk00, srcA), t0bA = __shfl((int)pk01, srcA);
    unsigned t1aA = __shfl((int)pk10, srcA), t1bA = __shfl((int)pk11, srcA);
    unsigned t0aB = __shfl((int)pk00, srcB), t0bB = __shfl((int)pk01, srcB);
    unsigned t1aB = __shfl((int)pk10, srcB), t1bB = __shfl((int)pk11, srcB);
    union { unsigned u[4]; short8_t v; } au;
    au.u[0] = hi ? t1aA : t0aA;
    au.u[1] = hi ? t1bA : t0bA;
    au.u[2] = hi ? t1aB : t0aB;
    au.u[3] = hi ? t1bB : t0bB;
    short8_t afrag = au.v;

    // ---- P@V: B-frags are 4 contiguous 16B loads in one 4 KB block
    const short* vk = vbat + ((size_t)(k0 >> 5) << 11);
    short8_t b0 = *(const short8_t*)(vk);
    short8_t b1 = *(const short8_t*)(vk + 128);
    short8_t b2 = *(const short8_t*)(vk + 256);
    short8_t b3 = *(const short8_t*)(vk + 384);
    acc[0] = __builtin_amdgcn_mfma_f32_16x16x32_bf16(afrag, b0, acc[0], 0, 0, 0);
    acc[1] = __builtin_amdgcn_mfma_f32_16x16x32_bf16(afrag, b1, acc[1], 0, 0, 0);
    acc[2] = __builtin_amdgcn_mfma_f32_16x16x32_bf16(afrag, b2, acc[2], 0, 0, 0);
    acc[3] = __builtin_amdgcn_mfma_f32_16x16x32_bf16(afrag, b3, acc[3], 0, 0, 0);
  }

  // per-wave l: sum over quads -> every lane holds l for q = l15
  float lv = lpart;
  lv += __shfl_xor(lv, 16);
  lv += __shfl_xor(lv, 32);

  // cross-wave combine
  if (w > 0) {
    float* p = &red[w - 1][lane][0];
#pragma unroll
    for (int ct = 0; ct < 4; ct++)
#pragma unroll
      for (int reg = 0; reg < 4; reg++) p[ct * 4 + reg] = acc[ct][reg];
    p[16] = lv;
  }
  __syncthreads();
  if (w == 0) {
#pragma unroll
    for (int ww = 0; ww < 7; ww++) {
      const float* p = &red[ww][lane][0];
#pragma unroll
      for (int ct = 0; ct < 4; ct++)
#pragma unroll
        for (int reg = 0; reg < 4; reg++) acc[ct][reg] += p[ct * 4 + reg];
      lv += p[16];
    }
    float inv[4];
#pragma unroll
    for (int reg = 0; reg < 4; reg++)
      inv[reg] = 1.0f / __shfl(lv, quad * 4 + reg);

    float* ob = out + ((size_t)b * N + q0) * 64 + l15;
#pragma unroll
    for (int reg = 0; reg < 4; reg++)
#pragma unroll
      for (int ct = 0; ct < 4; ct++)
        ob[(quad * 4 + reg) * 64 + ct * 16] = acc[ct][reg] * inv[reg];
  }
}

// ---------------------------------------------------------------------------
extern "C" void kernel_launch(void* const* d_in, const int* in_sizes, int n_in,
                              void* d_out, int out_size, void* d_ws, size_t ws_size,
                              hipStream_t stream) {
  const float* x  = (const float*)d_in[0];
  const float* Wf = (const float*)d_in[1];
  const float* bf = (const float*)d_in[2];
  const float* Wg = (const float*)d_in[3];
  const float* bg = (const float*)d_in[4];
  const float* Wh = (const float*)d_in[5];
  const float* bh = (const float*)d_in[6];
  float* out = (float*)d_out;

  char* ws = (char*)d_ws;
  _Float16* fh = (_Float16*)ws;                        // 4*4096*8*2  = 256 KB
  _Float16* gh = (_Float16*)(ws + 262144);             // 256 KB
  unsigned short* vT = (unsigned short*)(ws + 524288); // 4*64*4096*2 = 2 MB

  prep_kernel<<<512, 256, 0, stream>>>(x, Wf, bf, Wg, bg, Wh, bh, fh, gh, vT);
  attn_kernel<<<1024, 512, 0, stream>>>(fh, gh, vT, out);
}

// Round 5
// 106.177 us; speedup vs baseline: 1.5759x; 1.5759x over previous
//
#include <hip/hip_runtime.h>
#include <hip/hip_bf16.h>
#include <hip/hip_fp16.h>

typedef _Float16 half8_t __attribute__((ext_vector_type(8)));
typedef _Float16 half4_t __attribute__((ext_vector_type(4)));
typedef short    short8_t __attribute__((ext_vector_type(8)));
typedef float    f32x4    __attribute__((ext_vector_type(4)));

// ---------------------------------------------------------------------------
// Kernel 1 (v3): f = x@Wf+bf (f16), g = x@Wg+bg (f16),
// vT2 = x@Wh+bh (bf16) in MFMA-B-fragment tiling:
//   vT2[b][k>>5][(k>>3)&3][ch][k&7]   (per batch: 128*4*64*8 = 262144 shorts)
// so an attn B-frag (ch = l15+16ct, keys k0+quad*8..+7) is 16 contiguous bytes.
// 512 blocks x 256 thr; block = 32 positions; thread = 10 of 80 concat chans.
// ---------------------------------------------------------------------------
__global__ __launch_bounds__(256) void prep_kernel(
    const float* __restrict__ x,
    const float* __restrict__ Wf, const float* __restrict__ bf,
    const float* __restrict__ Wg, const float* __restrict__ bg,
    const float* __restrict__ Wh, const float* __restrict__ bh,
    _Float16* __restrict__ fh, _Float16* __restrict__ gh,
    unsigned short* __restrict__ vT)
{
  __shared__ float XsT[64 * 33];   // [c][pos], pad 33 -> conflict-free
  __shared__ float Wall[64 * 80];  // [c][ch]; ch 0-7 = Wf, 8-15 = Wg, 16-79 = Wh
  __shared__ float ball[80];
  const int t  = threadIdx.x;
  const int p0 = blockIdx.x * 32;  // flat position base (B*N)

  for (int i = t; i < 512; i += 256) {
    Wall[(i >> 3) * 80 + (i & 7)]     = Wf[i];
    Wall[(i >> 3) * 80 + 8 + (i & 7)] = Wg[i];
  }
  for (int i = t; i < 4096; i += 256)
    Wall[(i >> 6) * 80 + 16 + (i & 63)] = Wh[i];
  if (t < 80) ball[t] = (t < 8) ? bf[t] : (t < 16) ? bg[t - 8] : bh[t - 16];

  const float4* xs = (const float4*)(x + (size_t)p0 * 64);
#pragma unroll
  for (int i = 0; i < 2; i++) {
    int idx = t + i * 256;          // 512 float4 = 32 rows x 16
    int row = idx >> 4, c4 = idx & 15;
    float4 v = xs[idx];
    XsT[(c4 * 4 + 0) * 33 + row] = v.x;
    XsT[(c4 * 4 + 1) * 33 + row] = v.y;
    XsT[(c4 * 4 + 2) * 33 + row] = v.z;
    XsT[(c4 * 4 + 3) * 33 + row] = v.w;
  }
  __syncthreads();

  const int pos = t & 31;
  const int g   = t >> 5;          // 0..7
  const int cb  = g * 10;          // channel base (even -> float2-aligned)

  float acc[10];
#pragma unroll
  for (int j = 0; j < 10; j++) acc[j] = ball[cb + j];

  for (int c = 0; c < 64; c++) {
    float xv = XsT[c * 33 + pos];
    const float2* wr = (const float2*)&Wall[c * 80 + cb];
#pragma unroll
    for (int k = 0; k < 5; k++) {
      float2 w2 = wr[k];
      acc[2 * k]     += xv * w2.x;
      acc[2 * k + 1] += xv * w2.y;
    }
  }

  const size_t pg = (size_t)p0 + pos;
  const int b = (int)(pg >> 12);
  const int n = (int)(pg & 4095);
  // fragment-tiled vT base for this (b, n)
  const size_t vidx = (((size_t)b * 128 + (n >> 5)) * 4 + ((n >> 3) & 3)) * 512 + (n & 7);
#pragma unroll
  for (int j = 0; j < 10; j++) {
    int ch = cb + j;
    if (ch < 8) {
      fh[pg * 8 + ch] = (_Float16)acc[j];
    } else if (ch < 16) {
      gh[pg * 8 + (ch - 8)] = (_Float16)acc[j];
    } else {
      __hip_bfloat16 hv = __float2bfloat16(acc[j]);
      vT[vidx + (size_t)(ch - 16) * 8] = *(unsigned short*)&hv;
    }
  }
}

// ---------------------------------------------------------------------------
// Kernel 2 (v5): flash attention, no-max softmax (logits bounded << 88).
// 1024 blocks x 512 thr (8 waves). Block = one (batch, 16-query tile); wave w
// handles keys [w*512, w*512+512). Partial (acc, l) combined through LDS.
// __launch_bounds__(512,4): VGPR cap 128 -> NO SPILL (R4's (512,8) forced a
// 64-VGPR cap and spilled the accumulators to scratch: FETCH 117MB/WRITE 213MB).
// ---------------------------------------------------------------------------
__device__ __forceinline__ unsigned pack_bf16_2(float lo, float hi) {
  float2 f2; f2.x = lo; f2.y = hi;
  __hip_bfloat162 h2 = __float22bfloat162_rn(f2);
  return *reinterpret_cast<unsigned*>(&h2);
}

__global__ __launch_bounds__(512, 4) void attn_kernel(
    const _Float16* __restrict__ fh,        // [B][N][8] f16
    const _Float16* __restrict__ gh,        // [B][N][8] f16
    const unsigned short* __restrict__ vT,  // frag-tiled, see prep
    float* __restrict__ out)                // [B][N][64] f32
{
  const int N    = 4096;
  const int lane = threadIdx.x & 63;
  const int w    = threadIdx.x >> 6;       // 0..7
  const int quad = lane >> 4;
  const int l15  = lane & 15;

  __shared__ float red[7][64][17];  // waves 1-7: 16 acc + 1 l per lane

  // XCD swizzle: batch b on XCDs {2b,2b+1} -> f/g/vT stay in that L2 pair
  const int xcd = blockIdx.x & 7;
  const int b   = xcd >> 1;
  const int sub = ((blockIdx.x >> 3) << 1) + (xcd & 1);  // 0..255 query tile
  const int q0  = sub * 16;
  const int kbase = w * 512;

  const _Float16* fbase = fh + (size_t)b * N * 8;
  const _Float16* gbase = gh + (size_t)b * N * 8;
  // lane-fixed part of the frag-tiled vT address
  const short* vbat = (const short*)vT + (size_t)b * 262144 + (quad << 9) + (l15 << 3);

  // G B-frag: B[k=quad*8+j][n=q=l15]; only quad 0 carries real k (DK=8)
  half8_t gfrag = {};
  if (quad == 0) gfrag = *(const half8_t*)(gbase + (size_t)(q0 + l15) * 8);

  const f32x4 zc = {0.f, 0.f, 0.f, 0.f};
  f32x4 acc[4] = {zc, zc, zc, zc};   // D[q=quad*4+reg][chan=ct*16+l15]
  float lpart = 0.f;

  const int  srcA = ((quad & 1) << 5) + l15;  // source lanes for C->A transform
  const int  srcB = srcA + 16;
  const bool hi   = (quad >= 2);

#pragma unroll 8
  for (int cc = 0; cc < 16; cc++) {
    const int k0 = kbase + cc * 32;

    // ---- scores: S^T[key][q], two 16-key tiles; loads masked to quad 0
    half8_t f0 = {}, f1 = {};
    if (quad == 0) {
      f0 = *(const half8_t*)(fbase + (size_t)(k0 + l15) * 8);
      f1 = *(const half8_t*)(fbase + (size_t)(k0 + 16 + l15) * 8);
    }
    f32x4 s0 = __builtin_amdgcn_mfma_f32_16x16x32_f16(f0, gfrag, zc, 0, 0, 0);
    f32x4 s1 = __builtin_amdgcn_mfma_f32_16x16x32_f16(f1, gfrag, zc, 0, 0, 0);
    // lane holds S^T[key = k0 + 16t + quad*4 + reg][q = l15]

    float p00 = __expf(s0[0]), p01 = __expf(s0[1]), p02 = __expf(s0[2]), p03 = __expf(s0[3]);
    float p10 = __expf(s1[0]), p11 = __expf(s1[1]), p12 = __expf(s1[2]), p13 = __expf(s1[3]);
    lpart += (p00 + p01 + p02 + p03) + (p10 + p11 + p12 + p13);

    unsigned pk00 = pack_bf16_2(p00, p01), pk01 = pack_bf16_2(p02, p03);
    unsigned pk10 = pack_bf16_2(p10, p11), pk11 = pack_bf16_2(p12, p13);

    // C-layout -> A-layout: lane (quad,l15) needs P[q=l15][kk=quad*8+j]
    unsigned t0aA = __shfl((int)pk00, srcA), t0bA = __shfl((int)pk01, srcA);
    unsigned t1aA = __shfl((int)pk10, srcA), t1bA = __shfl((int)pk11, srcA);
    unsigned t0aB = __shfl((int)pk00, srcB), t0bB = __shfl((int)pk01, srcB);
    unsigned t1aB = __shfl((int)pk10, srcB), t1bB = __shfl((int)pk11, srcB);
    union { unsigned u[4]; short8_t v; } au;
    au.u[0] = hi ? t1aA : t0aA;
    au.u[1] = hi ? t1bA : t0bA;
    au.u[2] = hi ? t1aB : t0aB;
    au.u[3] = hi ? t1bB : t0bB;
    short8_t afrag = au.v;

    // ---- P@V: B-frags are 4 contiguous 16B loads in one 4 KB block
    const short* vk = vbat + ((size_t)(k0 >> 5) << 11);
    short8_t b0 = *(const short8_t*)(vk);
    short8_t b1 = *(const short8_t*)(vk + 128);
    short8_t b2 = *(const short8_t*)(vk + 256);
    short8_t b3 = *(const short8_t*)(vk + 384);
    acc[0] = __builtin_amdgcn_mfma_f32_16x16x32_bf16(afrag, b0, acc[0], 0, 0, 0);
    acc[1] = __builtin_amdgcn_mfma_f32_16x16x32_bf16(afrag, b1, acc[1], 0, 0, 0);
    acc[2] = __builtin_amdgcn_mfma_f32_16x16x32_bf16(afrag, b2, acc[2], 0, 0, 0);
    acc[3] = __builtin_amdgcn_mfma_f32_16x16x32_bf16(afrag, b3, acc[3], 0, 0, 0);
  }

  // per-wave l: sum over quads -> every lane holds l for q = l15
  float lv = lpart;
  lv += __shfl_xor(lv, 16);
  lv += __shfl_xor(lv, 32);

  // cross-wave combine
  if (w > 0) {
    float* p = &red[w - 1][lane][0];
#pragma unroll
    for (int ct = 0; ct < 4; ct++)
#pragma unroll
      for (int reg = 0; reg < 4; reg++) p[ct * 4 + reg] = acc[ct][reg];
    p[16] = lv;
  }
  __syncthreads();
  if (w == 0) {
#pragma unroll
    for (int ww = 0; ww < 7; ww++) {
      const float* p = &red[ww][lane][0];
#pragma unroll
      for (int ct = 0; ct < 4; ct++)
#pragma unroll
        for (int reg = 0; reg < 4; reg++) acc[ct][reg] += p[ct * 4 + reg];
      lv += p[16];
    }
    float inv[4];
#pragma unroll
    for (int reg = 0; reg < 4; reg++)
      inv[reg] = 1.0f / __shfl(lv, quad * 4 + reg);

    float* ob = out + ((size_t)b * N + q0) * 64 + l15;
#pragma unroll
    for (int reg = 0; reg < 4; reg++)
#pragma unroll
      for (int ct = 0; ct < 4; ct++)
        ob[(quad * 4 + reg) * 64 + ct * 16] = acc[ct][reg] * inv[reg];
  }
}

// ---------------------------------------------------------------------------
extern "C" void kernel_launch(void* const* d_in, const int* in_sizes, int n_in,
                              void* d_out, int out_size, void* d_ws, size_t ws_size,
                              hipStream_t stream) {
  const float* x  = (const float*)d_in[0];
  const float* Wf = (const float*)d_in[1];
  const float* bf = (const float*)d_in[2];
  const float* Wg = (const float*)d_in[3];
  const float* bg = (const float*)d_in[4];
  const float* Wh = (const float*)d_in[5];
  const float* bh = (const float*)d_in[6];
  float* out = (float*)d_out;

  char* ws = (char*)d_ws;
  _Float16* fh = (_Float16*)ws;                        // 4*4096*8*2  = 256 KB
  _Float16* gh = (_Float16*)(ws + 262144);             // 256 KB
  unsigned short* vT = (unsigned short*)(ws + 524288); // 4*64*4096*2 = 2 MB

  prep_kernel<<<512, 256, 0, stream>>>(x, Wf, bf, Wg, bg, Wh, bh, fh, gh, vT);
  attn_kernel<<<1024, 512, 0, stream>>>(fh, gh, vT, out);
}